// Round 4
// baseline (710.062 us; speedup 1.0000x reference)
//
#include <hip/hip_runtime.h>
#include <cmath>

#define NK 1024
#define ND 64
#define NB 32
#define NH 64
#define NW 64
#define NTOT (NB*NH*NW)   // 131072 query vectors

// d_ws layout: [0..1023] uint32 counts, [1024..2047] float cnorm

__global__ __launch_bounds__(1024) void vq_prep(const float* __restrict__ emb,
                                                unsigned int* __restrict__ counts,
                                                float* __restrict__ cnorm) {
    int k = threadIdx.x;  // 1024 threads, one per code
    counts[k] = 0u;
    const float4* row = reinterpret_cast<const float4*>(emb + (size_t)k * ND);
    float s = 0.0f;
#pragma unroll
    for (int i = 0; i < ND/4; ++i) {
        float4 v = row[i];
        s += v.x*v.x + v.y*v.y + v.z*v.z + v.w*v.w;
    }
    cnorm[k] = s;
}

// One query per lane. X (64 ch) lives in VGPRs; E rows + cnorm are wave-uniform
// -> scalar loads (SGPR operands into v_fma). No LDS in the main loop.
__global__ __launch_bounds__(256) void vq_main(const float* __restrict__ in,
                                               const float* __restrict__ emb,
                                               const float* __restrict__ cnorm,
                                               unsigned int* __restrict__ counts,
                                               float* __restrict__ out_idx,
                                               float* __restrict__ out_q) {
    const int q  = blockIdx.x * 256 + threadIdx.x;   // b*4096 + h*64 + w
    const int b  = q >> 12;
    const int hw = q & 4095;

    // ---- load my query: in[b, c, h, w], stride 4096 over c; coalesced over w
    const float* xbase = in + ((size_t)b << 18) + hw;
    float4 xv[16];
#pragma unroll
    for (int i = 0; i < 16; ++i) {
        xv[i].x = xbase[(size_t)(4*i + 0) << 12];
        xv[i].y = xbase[(size_t)(4*i + 1) << 12];
        xv[i].z = xbase[(size_t)(4*i + 2) << 12];
        xv[i].w = xbase[(size_t)(4*i + 3) << 12];
    }

    // ---- scan all 1024 codes; maximize m = dot - cn/2  (== argmin dist)
    float bestm = -3.4e38f;
    int   bi    = 0;
#pragma unroll 2
    for (int k = 0; k < NK; ++k) {
        const float4* er = reinterpret_cast<const float4*>(emb + ((size_t)k << 6));
        float d0 = 0.0f, d1 = 0.0f, d2 = 0.0f, d3 = 0.0f;
#pragma unroll
        for (int i = 0; i < 16; i += 4) {
            float4 e0 = er[i+0], e1 = er[i+1], e2 = er[i+2], e3 = er[i+3];
            d0 = fmaf(xv[i+0].x, e0.x, d0); d0 = fmaf(xv[i+0].y, e0.y, d0);
            d0 = fmaf(xv[i+0].z, e0.z, d0); d0 = fmaf(xv[i+0].w, e0.w, d0);
            d1 = fmaf(xv[i+1].x, e1.x, d1); d1 = fmaf(xv[i+1].y, e1.y, d1);
            d1 = fmaf(xv[i+1].z, e1.z, d1); d1 = fmaf(xv[i+1].w, e1.w, d1);
            d2 = fmaf(xv[i+2].x, e2.x, d2); d2 = fmaf(xv[i+2].y, e2.y, d2);
            d2 = fmaf(xv[i+2].z, e2.z, d2); d2 = fmaf(xv[i+2].w, e2.w, d2);
            d3 = fmaf(xv[i+3].x, e3.x, d3); d3 = fmaf(xv[i+3].y, e3.y, d3);
            d3 = fmaf(xv[i+3].w, e3.w, d3); d3 = fmaf(xv[i+3].z, e3.z, d3);
        }
        float dot = (d0 + d1) + (d2 + d3);
        float m = fmaf(cnorm[k], -0.5f, dot);
        if (m > bestm) { bestm = m; bi = k; }   // strict > == first-min ties
    }

    // ---- outputs ----
    out_idx[q] = (float)bi;
    atomicAdd(&counts[bi], 1u);

    // quantized (B,C,H,W): per-lane gather of emb[bi] (L2-hot), coalesced
    // stores over w for each channel
    const float4* er = reinterpret_cast<const float4*>(emb + ((size_t)bi << 6));
    float* ob = out_q + ((size_t)b << 18) + hw;
#pragma unroll
    for (int i = 0; i < 16; ++i) {
        float4 e = er[i];
        ob[(size_t)(4*i + 0) << 12] = e.x;
        ob[(size_t)(4*i + 1) << 12] = e.y;
        ob[(size_t)(4*i + 2) << 12] = e.z;
        ob[(size_t)(4*i + 3) << 12] = e.w;
    }
}

__global__ __launch_bounds__(1024) void vq_perp(const unsigned int* __restrict__ counts,
                                                float* __restrict__ out_p) {
    __shared__ float red[16];
    int tid = threadIdx.x;  // 1024
    float p = (float)counts[tid] * (1.0f / (float)NTOT);
    float t = p * logf(p + 1e-10f);
#pragma unroll
    for (int m = 1; m < 64; m <<= 1) t += __shfl_xor(t, m, 64);
    if ((tid & 63) == 0) red[tid >> 6] = t;
    __syncthreads();
    if (tid < 16) {
        float s = red[tid];
#pragma unroll
        for (int m = 1; m < 16; m <<= 1) s += __shfl_xor(s, m, 64);
        if (tid == 0) out_p[0] = expf(-s);
    }
}

extern "C" void kernel_launch(void* const* d_in, const int* in_sizes, int n_in,
                              void* d_out, int out_size, void* d_ws, size_t ws_size,
                              hipStream_t stream) {
    const float* in  = (const float*)d_in[0];   // (32, 64, 64, 64)
    const float* emb = (const float*)d_in[1];   // (1024, 64)
    float* out = (float*)d_out;

    unsigned int* counts = (unsigned int*)d_ws;
    float* cnorm = (float*)d_ws + NK;

    float* out_idx = out;                       // 131072
    float* out_q   = out + NTOT;                // 8388608
    float* out_p   = out + NTOT + (size_t)NTOT * ND;  // 1

    vq_prep<<<1, 1024, 0, stream>>>(emb, counts, cnorm);
    vq_main<<<NTOT/256, 256, 0, stream>>>(in, emb, cnorm, counts, out_idx, out_q);
    vq_perp<<<1, 1024, 0, stream>>>(counts, out_p);
}

// Round 5
// 243.640 us; speedup vs baseline: 2.9144x; 2.9144x over previous
//
#include <hip/hip_runtime.h>
#include <cmath>

#define NK 1024
#define ND 64
#define NB 32
#define NH 64
#define NW 64
#define NTOT (NB*NH*NW)   // 131072 query vectors

// d_ws layout: [0..1023] uint32 counts, [1024..2047] float cnorm

__global__ __launch_bounds__(1024) void vq_prep(const float* __restrict__ emb,
                                                unsigned int* __restrict__ counts,
                                                float* __restrict__ cnorm) {
    int k = threadIdx.x;  // 1024 threads, one per code
    counts[k] = 0u;
    const float4* row = reinterpret_cast<const float4*>(emb + (size_t)k * ND);
    float s = 0.0f;
#pragma unroll
    for (int i = 0; i < ND/4; ++i) {
        float4 v = row[i];
        s += v.x*v.x + v.y*v.y + v.z*v.z + v.w*v.w;
    }
    cnorm[k] = s;
}

// 8x8 register micro-tile per thread; block = 128 queries x 128-code chunks.
// LDS traffic halves vs the 4x4 version: (8+8) b128 reads per 256 FMA-instr.
__global__ __launch_bounds__(256, 2) void vq_main(const float* __restrict__ in,
                                                  const float* __restrict__ emb,
                                                  const float* __restrict__ cnorm,
                                                  unsigned int* __restrict__ counts,
                                                  float* __restrict__ out_idx,
                                                  float* __restrict__ out_q) {
    __shared__ float Xs[128][68];   // pad 68: 4-bank row stride, b128 16B-aligned
    __shared__ float Es[128][68];   // Es[kl][64] = cnorm[kc+kl]
    __shared__ int bidx_lds[128];

    const int blk = blockIdx.x;     // b*32 + h2 ; block covers h = 2*h2, 2*h2+1
    const int b   = blk >> 5;
    const int h0  = (blk & 31) << 1;
    const int tid = threadIdx.x;
    const int tk  = tid & 15;       // code group  (16)
    const int tq  = tid >> 4;       // query group (16)

    // ---- stage X: Xs[hl*64+w][c] = in[b, c, h0+hl, w] ----
    const float* inb = in + ((size_t)b << 18) + ((size_t)h0 << 6);
#pragma unroll
    for (int p = 0; p < 32; ++p) {
        int f = p * 256 + tid;      // f = c*128 + (hl*64+w); lanes -> consecutive w
        Xs[f & 127][f >> 7] = inb[(size_t)(f >> 7) * 4096 + (f & 127)];
    }

    float bestm[8];
    int   bi[8];
#pragma unroll
    for (int i = 0; i < 8; ++i) { bestm[i] = -3.4e38f; bi[i] = 0; }

    for (int ch = 0; ch < 8; ++ch) {
        const int kc = ch << 7;
        // ---- stage 128-code chunk (float4-coalesced) + cnorm in pad col ----
        {
            const int d4  = (tid & 15) << 2;
            const int kl0 = tid >> 4;
#pragma unroll
            for (int p = 0; p < 8; ++p) {
                int kl = kl0 + (p << 4);
                *reinterpret_cast<float4*>(&Es[kl][d4]) =
                    *reinterpret_cast<const float4*>(emb + ((size_t)(kc + kl) << 6) + d4);
            }
            if (tid < 128) Es[tid][64] = cnorm[kc + tid];
        }
        __syncthreads();

        float dot[8][8];
#pragma unroll
        for (int i = 0; i < 8; ++i)
#pragma unroll
            for (int j = 0; j < 8; ++j) dot[i][j] = 0.0f;

#pragma unroll
        for (int d4 = 0; d4 < 64; d4 += 4) {
            float4 xq[8], ek[8];
#pragma unroll
            for (int i = 0; i < 8; ++i)
                xq[i] = *reinterpret_cast<const float4*>(&Xs[tq + (i << 4)][d4]);
#pragma unroll
            for (int j = 0; j < 8; ++j)
                ek[j] = *reinterpret_cast<const float4*>(&Es[tk + (j << 4)][d4]);
#pragma unroll
            for (int i = 0; i < 8; ++i)
#pragma unroll
                for (int j = 0; j < 8; ++j) {
                    dot[i][j] = fmaf(xq[i].x, ek[j].x, dot[i][j]);
                    dot[i][j] = fmaf(xq[i].y, ek[j].y, dot[i][j]);
                    dot[i][j] = fmaf(xq[i].z, ek[j].z, dot[i][j]);
                    dot[i][j] = fmaf(xq[i].w, ek[j].w, dot[i][j]);
                }
        }

        // ---- m = dot - cn/2 (maximize == argmin dist); k ascending per lane ----
#pragma unroll
        for (int j = 0; j < 8; ++j) {
            const int k = kc + tk + (j << 4);
            const float cn = Es[tk + (j << 4)][64];
#pragma unroll
            for (int i = 0; i < 8; ++i) {
                float m = fmaf(cn, -0.5f, dot[i][j]);
                if (m > bestm[i]) { bestm[i] = m; bi[i] = k; }  // strict > = first-min
            }
        }
        __syncthreads();  // before next chunk overwrites Es
    }

    // ---- reduce over the 16 tk lanes sharing each query ----
#pragma unroll
    for (int mm = 1; mm < 16; mm <<= 1) {
#pragma unroll
        for (int i = 0; i < 8; ++i) {
            float ob = __shfl_xor(bestm[i], mm, 64);
            int   oi = __shfl_xor(bi[i],   mm, 64);
            if (ob > bestm[i] || (ob == bestm[i] && oi < bi[i])) { bestm[i] = ob; bi[i] = oi; }
        }
    }
    if (tk == 0) {
#pragma unroll
        for (int i = 0; i < 8; ++i) bidx_lds[tq + (i << 4)] = bi[i];
    }
    __syncthreads();

    // ---- indices (as float) + histogram ----
    if (tid < 128) {
        int idx = bidx_lds[tid];
        out_idx[((size_t)b << 12) + ((size_t)h0 << 6) + tid] = (float)idx;
        atomicAdd(&counts[idx], 1u);
    }

    // ---- quantized (B,C,H,W): gather emb rows (L2-hot), coalesced stores ----
    float* outb = out_q + ((size_t)b << 18) + ((size_t)h0 << 6);
#pragma unroll
    for (int p = 0; p < 32; ++p) {
        int f  = p * 256 + tid;
        int c  = f >> 7;
        int ql = f & 127;
        outb[(size_t)c * 4096 + ql] = emb[((size_t)bidx_lds[ql] << 6) + c];
    }
}

__global__ __launch_bounds__(1024) void vq_perp(const unsigned int* __restrict__ counts,
                                                float* __restrict__ out_p) {
    __shared__ float red[16];
    int tid = threadIdx.x;  // 1024
    float p = (float)counts[tid] * (1.0f / (float)NTOT);
    float t = p * logf(p + 1e-10f);
#pragma unroll
    for (int m = 1; m < 64; m <<= 1) t += __shfl_xor(t, m, 64);
    if ((tid & 63) == 0) red[tid >> 6] = t;
    __syncthreads();
    if (tid < 16) {
        float s = red[tid];
#pragma unroll
        for (int m = 1; m < 16; m <<= 1) s += __shfl_xor(s, m, 64);
        if (tid == 0) out_p[0] = expf(-s);
    }
}

extern "C" void kernel_launch(void* const* d_in, const int* in_sizes, int n_in,
                              void* d_out, int out_size, void* d_ws, size_t ws_size,
                              hipStream_t stream) {
    const float* in  = (const float*)d_in[0];   // (32, 64, 64, 64)
    const float* emb = (const float*)d_in[1];   // (1024, 64)
    float* out = (float*)d_out;

    unsigned int* counts = (unsigned int*)d_ws;
    float* cnorm = (float*)d_ws + NK;

    float* out_idx = out;                       // 131072
    float* out_q   = out + NTOT;                // 8388608
    float* out_p   = out + NTOT + (size_t)NTOT * ND;  // 1

    vq_prep<<<1, 1024, 0, stream>>>(emb, counts, cnorm);
    vq_main<<<NTOT/128, 256, 0, stream>>>(in, emb, cnorm, counts, out_idx, out_q);
    vq_perp<<<1, 1024, 0, stream>>>(counts, out_p);
}